// Round 5
// baseline (294.627 us; speedup 1.0000x reference)
//
#include <hip/hip_runtime.h>
#include <math.h>

// ---------------------------------------------------------------------------
// GCN. CSR build = bucketed counting sort, LDS atomics only (no global
// atomics: device-scope atomic-returns execute memory-side on multi-XCD
// CDNA4 at ~23 Gops/s — measured R3/R4 — so they are banned here).
//   P1: partition edges into NBC buckets of 512 nodes (dst>>9):
//       hist (LDS) -> scan of (bucket,block) matrix -> scatter to ebuf.
//   P2: per bucket: LDS hist+scan -> row_ptr/dinv; LDS rank -> colw.
// Aggregation: atomic-free gather, one wave per node, 8-wide edge batches.
// ---------------------------------------------------------------------------

#define TPB    256
#define EBLKS  128          // pass-1 edge blocks
#define BSH    9            // 512 nodes per bucket
#define BNODES (1 << BSH)

// P1a: OFS[c*EBLKS + b] = #edges of bucket c in block b's chunk
__global__ __launch_bounds__(TPB)
void k_p1hist(const int* __restrict__ dst, int* __restrict__ OFS,
              int E, int CH, int NBC) {
    __shared__ int h[512];
    int tid = threadIdx.x, b = blockIdx.x;
    for (int i = tid; i < NBC; i += TPB) h[i] = 0;
    __syncthreads();
    int beg = b * CH, end = min(E, beg + CH);
    int nfull = (end - beg) & ~3;
    for (int i = beg + tid * 4; i < beg + nfull; i += TPB * 4) {
        int4 d = *(const int4*)&dst[i];
        atomicAdd(&h[d.x >> BSH], 1);
        atomicAdd(&h[d.y >> BSH], 1);
        atomicAdd(&h[d.z >> BSH], 1);
        atomicAdd(&h[d.w >> BSH], 1);
    }
    if (tid < (end - beg) - nfull)
        atomicAdd(&h[dst[beg + nfull + tid] >> BSH], 1);
    __syncthreads();
    for (int c = tid; c < NBC; c += TPB) OFS[c * EBLKS + b] = h[c];
}

// P1b: exclusive scan of OFS[0..total) in place, sentinel OFS[total]=E
__global__ __launch_bounds__(TPB)
void k_p1scan(int* OFS, int total, int E) {
    __shared__ int s[TPB];
    int tid = threadIdx.x;
    int chunk = (total + TPB - 1) / TPB;
    int beg = tid * chunk, end = min(total, beg + chunk);
    int sum = 0;
    for (int i = beg; i < end; ++i) sum += OFS[i];
    s[tid] = sum;
    __syncthreads();
    for (int off = 1; off < TPB; off <<= 1) {
        int x = (tid >= off) ? s[tid - off] : 0;
        __syncthreads();
        s[tid] += x;
        __syncthreads();
    }
    int run = s[tid] - sum;
    for (int i = beg; i < end; ++i) {
        int v = OFS[i];
        OFS[i] = run;
        run += v;
    }
    if (tid == 0) OFS[total] = E;
}

// P1c: scatter (src,dst) into bucket-contiguous ebuf via LDS cursors
__global__ __launch_bounds__(TPB)
void k_p1scatter(const int* __restrict__ src, const int* __restrict__ dst,
                 const int* __restrict__ OFS, int2* __restrict__ ebuf,
                 int E, int CH, int NBC) {
    __shared__ int cur[512];
    int tid = threadIdx.x, b = blockIdx.x;
    for (int c = tid; c < NBC; c += TPB) cur[c] = OFS[c * EBLKS + b];
    __syncthreads();
    int beg = b * CH, end = min(E, beg + CH);
    int nfull = (end - beg) & ~3;
    for (int i = beg + tid * 4; i < beg + nfull; i += TPB * 4) {
        int4 s4 = *(const int4*)&src[i];
        int4 d4 = *(const int4*)&dst[i];
        int p0 = atomicAdd(&cur[d4.x >> BSH], 1);
        int p1 = atomicAdd(&cur[d4.y >> BSH], 1);
        int p2 = atomicAdd(&cur[d4.z >> BSH], 1);
        int p3 = atomicAdd(&cur[d4.w >> BSH], 1);
        ebuf[p0] = make_int2(s4.x, d4.x);
        ebuf[p1] = make_int2(s4.y, d4.y);
        ebuf[p2] = make_int2(s4.z, d4.z);
        ebuf[p3] = make_int2(s4.w, d4.w);
    }
    if (tid < (end - beg) - nfull) {
        int i = beg + nfull + tid;
        int d = dst[i];
        int p = atomicAdd(&cur[d >> BSH], 1);
        ebuf[p] = make_int2(src[i], d);
    }
}

// P2a: per bucket: LDS hist over 512 local nodes -> scan -> row_ptr, dinv
__global__ __launch_bounds__(TPB)
void k_p2rowptr(const int2* __restrict__ ebuf, const int* __restrict__ OFS,
                int* __restrict__ row_ptr, float* __restrict__ dinv,
                int N, int E, int NBC) {
    __shared__ int cnt[BNODES];
    __shared__ int s1[TPB];
    int tid = threadIdx.x, c = blockIdx.x;
    int beg = OFS[c * EBLKS], end = OFS[(c + 1) * EBLKS];
    for (int i = tid; i < BNODES; i += TPB) cnt[i] = 0;
    __syncthreads();
    for (int i = beg + tid; i < end; i += TPB)
        atomicAdd(&cnt[ebuf[i].y & (BNODES - 1)], 1);
    __syncthreads();
    int a0 = cnt[2 * tid], a1 = cnt[2 * tid + 1];
    int pairsum = a0 + a1;
    s1[tid] = pairsum;
    __syncthreads();
    for (int off = 1; off < TPB; off <<= 1) {
        int x = (tid >= off) ? s1[tid - off] : 0;
        __syncthreads();
        s1[tid] += x;
        __syncthreads();
    }
    int ex = s1[tid] - pairsum;
    int node0 = (c << BSH) + 2 * tid;
    if (node0 < N) {
        row_ptr[node0] = beg + ex;
        dinv[node0]    = rsqrtf((float)(a0 + 1));
    }
    if (node0 + 1 < N) {
        row_ptr[node0 + 1] = beg + ex + a0;
        dinv[node0 + 1]    = rsqrtf((float)(a1 + 1));
    }
    if (c == NBC - 1 && tid == 0) row_ptr[N] = E;
}

// P2b: per bucket: LDS rank -> colw[row_ptr[d]+rank] = {src, dinv[s]*dinv[d]}
__global__ __launch_bounds__(TPB)
void k_p2fill(const int2* __restrict__ ebuf, const int* __restrict__ OFS,
              const int* __restrict__ row_ptr, const float* __restrict__ dinv,
              int2* __restrict__ colw, int NBC) {
    __shared__ int cnt[BNODES];
    int tid = threadIdx.x, c = blockIdx.x;
    int beg = OFS[c * EBLKS], end = OFS[(c + 1) * EBLKS];
    for (int i = tid; i < BNODES; i += TPB) cnt[i] = 0;
    __syncthreads();
    for (int i0 = beg + tid; i0 < end; i0 += TPB * 4) {
        int2  e[4];
        int   pos[4];
        float w[4];
        int   have = 0;
#pragma unroll
        for (int k = 0; k < 4; ++k) {
            int i = i0 + k * TPB;
            if (i < end) { e[k] = ebuf[i]; have = k + 1; }
        }
#pragma unroll
        for (int k = 0; k < 4; ++k) {
            if (k < have) {
                int r  = atomicAdd(&cnt[e[k].y & (BNODES - 1)], 1);
                pos[k] = row_ptr[e[k].y] + r;
                w[k]   = dinv[e[k].x] * dinv[e[k].y];
            }
        }
#pragma unroll
        for (int k = 0; k < 4; ++k)
            if (k < have) colw[pos[k]] = make_int2(e[k].x, __float_as_int(w[k]));
    }
}

// Dense GEMM: [n,64] @ [64,F], writes t_out = in@W (+bias if FINAL).
template <int F, bool FINAL>
__launch_bounds__(256)
__global__ void k_mm(const float* __restrict__ in, const float* __restrict__ W,
                     const float* __restrict__ bias,
                     float* __restrict__ t_out, int n) {
    __shared__ float in_s[64 * 68];
    __shared__ float w_s[64 * F];

    const int tid  = threadIdx.x;
    const int row0 = blockIdx.x * 64;

    for (int i4 = tid; i4 < (64 * F) / 4; i4 += 256)
        ((float4*)w_s)[i4] = ((const float4*)W)[i4];

    for (int idx = tid; idx < 64 * 16; idx += 256) {
        int r  = idx >> 4;
        int c4 = idx & 15;
        float4 v;
        if (row0 + r < n)
            v = *(const float4*)&in[(size_t)(row0 + r) * 64 + c4 * 4];
        else
            v = make_float4(0.f, 0.f, 0.f, 0.f);
        *(float4*)&in_s[r * 68 + c4 * 4] = v;
    }
    __syncthreads();

    constexpr int CPT = F / 16;
    const int tx = tid & 15;
    const int ty = tid >> 4;

    float acc[4][CPT];
#pragma unroll
    for (int r = 0; r < 4; ++r)
#pragma unroll
        for (int c = 0; c < CPT; ++c) acc[r][c] = 0.f;

#pragma unroll 4
    for (int k = 0; k < 64; ++k) {
        float b[CPT];
#pragma unroll
        for (int c = 0; c < CPT; ++c) b[c] = w_s[k * F + tx * CPT + c];
#pragma unroll
        for (int r = 0; r < 4; ++r) {
            float a = in_s[(ty * 4 + r) * 68 + k];
#pragma unroll
            for (int c = 0; c < CPT; ++c) acc[r][c] = fmaf(a, b[c], acc[r][c]);
        }
    }

#pragma unroll
    for (int r = 0; r < 4; ++r) {
        int row = row0 + ty * 4 + r;
        if (row >= n) continue;
#pragma unroll
        for (int c = 0; c < CPT; ++c) {
            int col = tx * CPT + c;
            float v = acc[r][c];
            if constexpr (FINAL) v += bias[col];
            t_out[(size_t)row * F + col] = v;
        }
    }
}

// Gather aggregation: one wave per dst node, lane = feature.
// agg[d] = relu(bias + dinv[d]^2 * t[d] + sum_e w_e * t[src_e])
__global__ __launch_bounds__(256)
void k_gather(const int* __restrict__ row_ptr, const int2* __restrict__ colw,
              const float* __restrict__ dinv, const float* __restrict__ bias,
              const float* __restrict__ t, float* __restrict__ agg, int N) {
    int gid  = blockIdx.x * blockDim.x + threadIdx.x;
    int d    = gid >> 6;
    int lane = threadIdx.x & 63;
    if (d >= N) return;

    int beg = row_ptr[d], end = row_ptr[d + 1];
    float dd  = dinv[d];
    float acc = bias[lane] + dd * dd * t[(size_t)d * 64 + lane];

    for (int base = beg; base < end; base += 64) {
        int nc = end - base;
        if (nc > 64) nc = 64;
        int2 cw = (lane < nc) ? colw[base + lane] : make_int2(0, 0);
        for (int j = 0; j < nc; j += 8) {
            int   s[8];
            float w[8];
#pragma unroll
            for (int k = 0; k < 8; ++k) {
                s[k] = __shfl(cw.x, j + k);
                w[k] = __int_as_float(__shfl(cw.y, j + k));
            }
            float v[8];
#pragma unroll
            for (int k = 0; k < 8; ++k)
                v[k] = t[(size_t)s[k] * 64 + lane];
#pragma unroll
            for (int k = 0; k < 8; ++k)
                acc = fmaf(w[k], v[k], acc);
        }
    }
    agg[(size_t)d * 64 + lane] = fmaxf(acc, 0.f);
}

extern "C" void kernel_launch(void* const* d_in, const int* in_sizes, int n_in,
                              void* d_out, int out_size, void* d_ws, size_t ws_size,
                              hipStream_t stream) {
    const float* x  = (const float*)d_in[0];
    const int*   ei = (const int*)d_in[1];
    const float* W1 = (const float*)d_in[2];
    const float* b1 = (const float*)d_in[3];
    const float* W2 = (const float*)d_in[4];
    const float* b2 = (const float*)d_in[5];
    const float* Wl = (const float*)d_in[6];
    const float* bl = (const float*)d_in[7];
    float*       out = (float*)d_out;

    const int N = in_sizes[0] / 64;
    const int E = in_sizes[1] / 2;
    const int* srcp = ei;
    const int* dstp = ei + E;

    const int NBC = (N + BNODES - 1) / BNODES;          // buckets
    const int CH  = (((E + EBLKS - 1) / EBLKS) + 3) & ~3;  // chunk, mult of 4

    char*  ws  = (char*)d_ws;
    size_t off = 0;
    auto alloc = [&](size_t bytes) -> void* {
        void* p = (void*)(ws + off);
        off += (bytes + 255) & ~(size_t)255;
        return p;
    };
    int*   OFS     = (int*)alloc(((size_t)NBC * EBLKS + 1) * 4);
    int2*  ebuf    = (int2*)alloc((size_t)E * 8);
    int*   row_ptr = (int*)alloc((size_t)(N + 1) * 4);
    float* dinv    = (float*)alloc((size_t)N * 4);
    int2*  colw    = (int2*)alloc((size_t)E * 8);
    float* t       = (float*)alloc((size_t)N * 64 * 4);
    float* agg1    = (float*)alloc((size_t)N * 64 * 4);
    float* agg2    = agg1;   // safe: agg1 dead once mm2 wrote t

    const int nb_mm = (N + 63) / 64;
    const int nb_g  = (int)(((size_t)N * 64 + 255) / 256);

    // --- CSR build (no global atomics) ---
    k_p1hist   <<<EBLKS, TPB, 0, stream>>>(dstp, OFS, E, CH, NBC);
    k_p1scan   <<<1,     TPB, 0, stream>>>(OFS, NBC * EBLKS, E);
    k_p1scatter<<<EBLKS, TPB, 0, stream>>>(srcp, dstp, OFS, ebuf, E, CH, NBC);
    k_p2rowptr <<<NBC,   TPB, 0, stream>>>(ebuf, OFS, row_ptr, dinv, N, E, NBC);
    k_p2fill   <<<NBC,   TPB, 0, stream>>>(ebuf, OFS, row_ptr, dinv, colw, NBC);

    // --- layer 1 ---
    k_mm<64, false><<<nb_mm, 256, 0, stream>>>(x, W1, nullptr, t, N);
    k_gather<<<nb_g, 256, 0, stream>>>(row_ptr, colw, dinv, b1, t, agg1, N);

    // --- layer 2 ---
    k_mm<64, false><<<nb_mm, 256, 0, stream>>>(agg1, W2, nullptr, t, N);
    k_gather<<<nb_g, 256, 0, stream>>>(row_ptr, colw, dinv, b2, t, agg2, N);

    // --- head ---
    k_mm<32, true><<<nb_mm, 256, 0, stream>>>(agg2, Wl, bl, out, N);
}

// Round 6
// 255.922 us; speedup vs baseline: 1.1512x; 1.1512x over previous
//
#include <hip/hip_runtime.h>
#include <math.h>

// ---------------------------------------------------------------------------
// GCN. CSR build = bucketed counting sort, LDS atomics only (no global
// atomics: device-scope atomic-returns execute memory-side on multi-XCD
// CDNA4 at ~23 Gops/s — measured R3/R4 — so they are banned here).
//   P1: partition edges into NBC buckets of 512 nodes (dst>>9):
//       hist (LDS) -> hierarchical scan of (bucket,block) matrix -> scatter.
//   P2: per bucket: LDS hist+scan -> row_ptr/dinv; LDS rank -> colw.
// Aggregation: atomic-free gather, one wave per node, 8-wide edge batches.
// ---------------------------------------------------------------------------

#define TPB    256
#define EBLKS  256          // pass-1 edge blocks (256 -> all CUs busy)
#define BSH    9            // 512 nodes per bucket
#define BNODES (1 << BSH)

// P1a: OFS[c*EBLKS + b] = #edges of bucket c in block b's chunk
__global__ __launch_bounds__(TPB)
void k_p1hist(const int* __restrict__ dst, int* __restrict__ OFS,
              int E, int CH, int NBC) {
    __shared__ int h[512];
    int tid = threadIdx.x, b = blockIdx.x;
    for (int i = tid; i < NBC; i += TPB) h[i] = 0;
    __syncthreads();
    int beg = b * CH, end = min(E, beg + CH);
    if (beg < end) {
        int nfull = (end - beg) & ~3;
        for (int i = beg + tid * 4; i < beg + nfull; i += TPB * 4) {
            int4 d = *(const int4*)&dst[i];
            atomicAdd(&h[d.x >> BSH], 1);
            atomicAdd(&h[d.y >> BSH], 1);
            atomicAdd(&h[d.z >> BSH], 1);
            atomicAdd(&h[d.w >> BSH], 1);
        }
        if (tid < (end - beg) - nfull)
            atomicAdd(&h[dst[beg + nfull + tid] >> BSH], 1);
    }
    __syncthreads();
    for (int c = tid; c < NBC; c += TPB) OFS[c * EBLKS + b] = h[c];
}

// Hierarchical exclusive scan of OFS[0..total): A per-block sums,
// B one-block scan of sums (+ sentinel), C apply + intra-block scan.
__global__ __launch_bounds__(TPB)
void k_scanA(const int* __restrict__ OFS, int* __restrict__ bsum, int total) {
    __shared__ int s[TPB];
    int tid = threadIdx.x;
    int i0  = blockIdx.x * 1024 + tid * 4;
    int t = 0;
#pragma unroll
    for (int k = 0; k < 4; ++k) {
        int i = i0 + k;
        t += (i < total) ? OFS[i] : 0;
    }
    s[tid] = t;
    __syncthreads();
    for (int off = TPB / 2; off > 0; off >>= 1) {
        if (tid < off) s[tid] += s[tid + off];
        __syncthreads();
    }
    if (tid == 0) bsum[blockIdx.x] = s[0];
}

__global__ __launch_bounds__(TPB)
void k_scanB(int* bsum, int* OFS, int NBLK, int total, int E) {
    __shared__ int s[TPB];
    int tid = threadIdx.x;
    int v = (tid < NBLK) ? bsum[tid] : 0;
    s[tid] = v;
    __syncthreads();
    for (int off = 1; off < TPB; off <<= 1) {
        int x = (tid >= off) ? s[tid - off] : 0;
        __syncthreads();
        s[tid] += x;
        __syncthreads();
    }
    if (tid < NBLK) bsum[tid] = s[tid] - v;   // exclusive
    if (tid == 0) OFS[total] = E;             // sentinel
}

__global__ __launch_bounds__(TPB)
void k_scanC(int* __restrict__ OFS, const int* __restrict__ bsum, int total) {
    __shared__ int s[TPB];
    int tid = threadIdx.x;
    int i0  = blockIdx.x * 1024 + tid * 4;
    int v[4];
#pragma unroll
    for (int k = 0; k < 4; ++k) {
        int i = i0 + k;
        v[k] = (i < total) ? OFS[i] : 0;
    }
    int tsum = v[0] + v[1] + v[2] + v[3];
    s[tid] = tsum;
    __syncthreads();
    for (int off = 1; off < TPB; off <<= 1) {
        int x = (tid >= off) ? s[tid - off] : 0;
        __syncthreads();
        s[tid] += x;
        __syncthreads();
    }
    int base = bsum[blockIdx.x] + (s[tid] - tsum);
#pragma unroll
    for (int k = 0; k < 4; ++k) {
        int i = i0 + k;
        if (i < total) {
            OFS[i] = base;
            base += v[k];
        }
    }
}

// P1c: scatter (src,dst) into bucket-contiguous ebuf via LDS cursors
__global__ __launch_bounds__(TPB)
void k_p1scatter(const int* __restrict__ src, const int* __restrict__ dst,
                 const int* __restrict__ OFS, int2* __restrict__ ebuf,
                 int E, int CH, int NBC) {
    __shared__ int cur[512];
    int tid = threadIdx.x, b = blockIdx.x;
    for (int c = tid; c < NBC; c += TPB) cur[c] = OFS[c * EBLKS + b];
    __syncthreads();
    int beg = b * CH, end = min(E, beg + CH);
    if (beg >= end) return;
    int nfull = (end - beg) & ~3;
    for (int i = beg + tid * 4; i < beg + nfull; i += TPB * 4) {
        int4 s4 = *(const int4*)&src[i];
        int4 d4 = *(const int4*)&dst[i];
        int p0 = atomicAdd(&cur[d4.x >> BSH], 1);
        int p1 = atomicAdd(&cur[d4.y >> BSH], 1);
        int p2 = atomicAdd(&cur[d4.z >> BSH], 1);
        int p3 = atomicAdd(&cur[d4.w >> BSH], 1);
        ebuf[p0] = make_int2(s4.x, d4.x);
        ebuf[p1] = make_int2(s4.y, d4.y);
        ebuf[p2] = make_int2(s4.z, d4.z);
        ebuf[p3] = make_int2(s4.w, d4.w);
    }
    if (tid < (end - beg) - nfull) {
        int i = beg + nfull + tid;
        int d = dst[i];
        int p = atomicAdd(&cur[d >> BSH], 1);
        ebuf[p] = make_int2(src[i], d);
    }
}

// P2a: per bucket: LDS hist over 512 local nodes -> scan -> row_ptr, dinv
__global__ __launch_bounds__(TPB)
void k_p2rowptr(const int2* __restrict__ ebuf, const int* __restrict__ OFS,
                int* __restrict__ row_ptr, float* __restrict__ dinv,
                int N, int E, int NBC) {
    __shared__ int cnt[BNODES];
    __shared__ int s1[TPB];
    int tid = threadIdx.x, c = blockIdx.x;
    int beg = OFS[c * EBLKS], end = OFS[(c + 1) * EBLKS];
    for (int i = tid; i < BNODES; i += TPB) cnt[i] = 0;
    __syncthreads();
    for (int i = beg + tid; i < end; i += TPB)
        atomicAdd(&cnt[ebuf[i].y & (BNODES - 1)], 1);
    __syncthreads();
    int a0 = cnt[2 * tid], a1 = cnt[2 * tid + 1];
    int pairsum = a0 + a1;
    s1[tid] = pairsum;
    __syncthreads();
    for (int off = 1; off < TPB; off <<= 1) {
        int x = (tid >= off) ? s1[tid - off] : 0;
        __syncthreads();
        s1[tid] += x;
        __syncthreads();
    }
    int ex = s1[tid] - pairsum;
    int node0 = (c << BSH) + 2 * tid;
    if (node0 < N) {
        row_ptr[node0] = beg + ex;
        dinv[node0]    = rsqrtf((float)(a0 + 1));
    }
    if (node0 + 1 < N) {
        row_ptr[node0 + 1] = beg + ex + a0;
        dinv[node0 + 1]    = rsqrtf((float)(a1 + 1));
    }
    if (c == NBC - 1 && tid == 0) row_ptr[N] = E;
}

// P2b: per bucket: LDS rank -> colw[row_ptr[d]+rank] = {src, dinv[s]*dinv[d]}
__global__ __launch_bounds__(TPB)
void k_p2fill(const int2* __restrict__ ebuf, const int* __restrict__ OFS,
              const int* __restrict__ row_ptr, const float* __restrict__ dinv,
              int2* __restrict__ colw, int NBC) {
    __shared__ int cnt[BNODES];
    int tid = threadIdx.x, c = blockIdx.x;
    int beg = OFS[c * EBLKS], end = OFS[(c + 1) * EBLKS];
    for (int i = tid; i < BNODES; i += TPB) cnt[i] = 0;
    __syncthreads();
    for (int i0 = beg + tid; i0 < end; i0 += TPB * 4) {
        int2  e[4];
        int   pos[4];
        float w[4];
        int   have = 0;
#pragma unroll
        for (int k = 0; k < 4; ++k) {
            int i = i0 + k * TPB;
            if (i < end) { e[k] = ebuf[i]; have = k + 1; }
        }
#pragma unroll
        for (int k = 0; k < 4; ++k) {
            if (k < have) {
                int r  = atomicAdd(&cnt[e[k].y & (BNODES - 1)], 1);
                pos[k] = row_ptr[e[k].y] + r;
                w[k]   = dinv[e[k].x] * dinv[e[k].y];
            }
        }
#pragma unroll
        for (int k = 0; k < 4; ++k)
            if (k < have) colw[pos[k]] = make_int2(e[k].x, __float_as_int(w[k]));
    }
}

// Dense GEMM: [n,64] @ [64,F], writes t_out = in@W (+bias if FINAL).
template <int F, bool FINAL>
__launch_bounds__(256)
__global__ void k_mm(const float* __restrict__ in, const float* __restrict__ W,
                     const float* __restrict__ bias,
                     float* __restrict__ t_out, int n) {
    __shared__ float in_s[64 * 68];
    __shared__ float w_s[64 * F];

    const int tid  = threadIdx.x;
    const int row0 = blockIdx.x * 64;

    for (int i4 = tid; i4 < (64 * F) / 4; i4 += 256)
        ((float4*)w_s)[i4] = ((const float4*)W)[i4];

    for (int idx = tid; idx < 64 * 16; idx += 256) {
        int r  = idx >> 4;
        int c4 = idx & 15;
        float4 v;
        if (row0 + r < n)
            v = *(const float4*)&in[(size_t)(row0 + r) * 64 + c4 * 4];
        else
            v = make_float4(0.f, 0.f, 0.f, 0.f);
        *(float4*)&in_s[r * 68 + c4 * 4] = v;
    }
    __syncthreads();

    constexpr int CPT = F / 16;
    const int tx = tid & 15;
    const int ty = tid >> 4;

    float acc[4][CPT];
#pragma unroll
    for (int r = 0; r < 4; ++r)
#pragma unroll
        for (int c = 0; c < CPT; ++c) acc[r][c] = 0.f;

#pragma unroll 4
    for (int k = 0; k < 64; ++k) {
        float b[CPT];
#pragma unroll
        for (int c = 0; c < CPT; ++c) b[c] = w_s[k * F + tx * CPT + c];
#pragma unroll
        for (int r = 0; r < 4; ++r) {
            float a = in_s[(ty * 4 + r) * 68 + k];
#pragma unroll
            for (int c = 0; c < CPT; ++c) acc[r][c] = fmaf(a, b[c], acc[r][c]);
        }
    }

#pragma unroll
    for (int r = 0; r < 4; ++r) {
        int row = row0 + ty * 4 + r;
        if (row >= n) continue;
#pragma unroll
        for (int c = 0; c < CPT; ++c) {
            int col = tx * CPT + c;
            float v = acc[r][c];
            if constexpr (FINAL) v += bias[col];
            t_out[(size_t)row * F + col] = v;
        }
    }
}

// Gather aggregation: one wave per dst node, lane = feature.
// agg[d] = relu(bias + dinv[d]^2 * t[d] + sum_e w_e * t[src_e])
__global__ __launch_bounds__(256)
void k_gather(const int* __restrict__ row_ptr, const int2* __restrict__ colw,
              const float* __restrict__ dinv, const float* __restrict__ bias,
              const float* __restrict__ t, float* __restrict__ agg, int N) {
    int gid  = blockIdx.x * blockDim.x + threadIdx.x;
    int d    = gid >> 6;
    int lane = threadIdx.x & 63;
    if (d >= N) return;

    int beg = row_ptr[d], end = row_ptr[d + 1];
    float dd  = dinv[d];
    float acc = bias[lane] + dd * dd * t[(size_t)d * 64 + lane];

    for (int base = beg; base < end; base += 64) {
        int nc = end - base;
        if (nc > 64) nc = 64;
        int2 cw = (lane < nc) ? colw[base + lane] : make_int2(0, 0);
        for (int j = 0; j < nc; j += 8) {
            int   s[8];
            float w[8];
#pragma unroll
            for (int k = 0; k < 8; ++k) {
                s[k] = __shfl(cw.x, j + k);
                w[k] = __int_as_float(__shfl(cw.y, j + k));
            }
            float v[8];
#pragma unroll
            for (int k = 0; k < 8; ++k)
                v[k] = t[(size_t)s[k] * 64 + lane];
#pragma unroll
            for (int k = 0; k < 8; ++k)
                acc = fmaf(w[k], v[k], acc);
        }
    }
    agg[(size_t)d * 64 + lane] = fmaxf(acc, 0.f);
}

extern "C" void kernel_launch(void* const* d_in, const int* in_sizes, int n_in,
                              void* d_out, int out_size, void* d_ws, size_t ws_size,
                              hipStream_t stream) {
    const float* x  = (const float*)d_in[0];
    const int*   ei = (const int*)d_in[1];
    const float* W1 = (const float*)d_in[2];
    const float* b1 = (const float*)d_in[3];
    const float* W2 = (const float*)d_in[4];
    const float* b2 = (const float*)d_in[5];
    const float* Wl = (const float*)d_in[6];
    const float* bl = (const float*)d_in[7];
    float*       out = (float*)d_out;

    const int N = in_sizes[0] / 64;
    const int E = in_sizes[1] / 2;
    const int* srcp = ei;
    const int* dstp = ei + E;

    const int NBC   = (N + BNODES - 1) / BNODES;             // buckets
    const int CH    = (((E + EBLKS - 1) / EBLKS) + 3) & ~3;  // chunk, mult of 4
    const int total = NBC * EBLKS;                           // offset matrix
    const int NBLK  = (total + 1023) / 1024;                 // scan blocks

    char*  ws  = (char*)d_ws;
    size_t off = 0;
    auto alloc = [&](size_t bytes) -> void* {
        void* p = (void*)(ws + off);
        off += (bytes + 255) & ~(size_t)255;
        return p;
    };
    int*   OFS     = (int*)alloc(((size_t)total + 1) * 4);
    int*   bsum    = (int*)alloc((size_t)NBLK * 4);
    int2*  ebuf    = (int2*)alloc((size_t)E * 8);
    int*   row_ptr = (int*)alloc((size_t)(N + 1) * 4);
    float* dinv    = (float*)alloc((size_t)N * 4);
    int2*  colw    = (int2*)alloc((size_t)E * 8);
    float* t       = (float*)alloc((size_t)N * 64 * 4);
    float* agg1    = (float*)alloc((size_t)N * 64 * 4);
    float* agg2    = agg1;   // safe: agg1 dead once mm2 wrote t

    const int nb_mm = (N + 63) / 64;
    const int nb_g  = (int)(((size_t)N * 64 + 255) / 256);

    // --- CSR build (no global atomics) ---
    k_p1hist   <<<EBLKS, TPB, 0, stream>>>(dstp, OFS, E, CH, NBC);
    k_scanA    <<<NBLK,  TPB, 0, stream>>>(OFS, bsum, total);
    k_scanB    <<<1,     TPB, 0, stream>>>(bsum, OFS, NBLK, total, E);
    k_scanC    <<<NBLK,  TPB, 0, stream>>>(OFS, bsum, total);
    k_p1scatter<<<EBLKS, TPB, 0, stream>>>(srcp, dstp, OFS, ebuf, E, CH, NBC);
    k_p2rowptr <<<NBC,   TPB, 0, stream>>>(ebuf, OFS, row_ptr, dinv, N, E, NBC);
    k_p2fill   <<<NBC,   TPB, 0, stream>>>(ebuf, OFS, row_ptr, dinv, colw, NBC);

    // --- layer 1 ---
    k_mm<64, false><<<nb_mm, 256, 0, stream>>>(x, W1, nullptr, t, N);
    k_gather<<<nb_g, 256, 0, stream>>>(row_ptr, colw, dinv, b1, t, agg1, N);

    // --- layer 2 ---
    k_mm<64, false><<<nb_mm, 256, 0, stream>>>(agg1, W2, nullptr, t, N);
    k_gather<<<nb_g, 256, 0, stream>>>(row_ptr, colw, dinv, b2, t, agg2, N);

    // --- head ---
    k_mm<32, true><<<nb_mm, 256, 0, stream>>>(agg2, Wl, bl, out, N);
}